// Round 12
// baseline (133.929 us; speedup 1.0000x reference)
//
#include <hip/hip_runtime.h>

typedef unsigned long long ull;

#define NA 147456
#define NB 16
#define NBINS 16384        // top-14 bits of monotonic key
#define CAND_CAP 2048
#define SEG 128            // CAND_CAP / 16 chunks
#define NPOST 1000

// ws layout (bytes)  (ws is ~268 MB)
#define OFF_CAND    0                    // 16*2048*8       = 262144
#define OFF_MASK    262144               // 16*1000*16*8    = 2048000 (maskT)
#define OFF_HP      2310144              // 256*16384*2     = 8388608 (private u16 hists)
#define OFF_PART    10698752             // 256*8           = 2048
#define OFF_META    10700800             // 16*16           = 256
#define OFF_SBOX    10701056             // 16*1000*16      = 256000
#define OFF_SSCORE  10957056             // 16*1000*4       = 64000
#define OFF_TICK    11021312             // 2*16*4          = 128 (zeroed each call)

__device__ __forceinline__ unsigned mkey(float f) {
  unsigned u = __float_as_uint(f);
  return u ^ ((unsigned)((int)u >> 31) | 0x80000000u);  // monotonic: bigger float -> bigger key
}

// ---------------- K1: softmax-reduce + private hist + inline threshold -------
// 256 blocks; the 16th block to finish a batch (ticket) sums the 16 private
// hists and computes (m, S, threshold bin) -> meta[b]. No separate launch.
__global__ __launch_bounds__(256) void k_reduce_hist(const float* __restrict__ labels,
                                                     unsigned short* __restrict__ hp,
                                                     float2* __restrict__ partial,
                                                     unsigned* __restrict__ tick,
                                                     float4* __restrict__ meta) {
  int b = blockIdx.x >> 4, blk = blockIdx.x & 15;
  __shared__ unsigned lh[NBINS];           // 64KB
  __shared__ float rm[256], rs[256];
  __shared__ int fin;
  int tid = threadIdx.x;
  for (int i = tid; i < NBINS; i += 256) lh[i] = 0;
  __syncthreads();

  const int chunk = NA / 16;               // 9216 floats = 2304 float4
  const float4* row4 = (const float4*)(labels + (size_t)b * NA + blk * chunk);

  float4 v[9];
#pragma unroll
  for (int it = 0; it < 9; ++it)
    v[it] = row4[it * 256 + tid];

#pragma unroll
  for (int it = 0; it < 9; ++it) {
    atomicAdd(&lh[mkey(v[it].x) >> 18], 1u);
    atomicAdd(&lh[mkey(v[it].y) >> 18], 1u);
    atomicAdd(&lh[mkey(v[it].z) >> 18], 1u);
    atomicAdd(&lh[mkey(v[it].w) >> 18], 1u);
  }

  float m = -INFINITY;
#pragma unroll
  for (int it = 0; it < 9; ++it)
    m = fmaxf(m, fmaxf(fmaxf(v[it].x, v[it].y), fmaxf(v[it].z, v[it].w)));
  float s = 0.f;
#pragma unroll
  for (int it = 0; it < 9; ++it) {
    s += expf(v[it].x - m); s += expf(v[it].y - m);
    s += expf(v[it].z - m); s += expf(v[it].w - m);
  }

  rm[tid] = m; rs[tid] = s;
  __syncthreads();
  for (int off = 128; off > 0; off >>= 1) {
    if (tid < off) {
      float m1 = rm[tid], s1 = rs[tid];
      float m2 = rm[tid + off], s2 = rs[tid + off];
      float M = fmaxf(m1, m2);
      rm[tid] = M;
      rs[tid] = s1 * expf(m1 - M) + s2 * expf(m2 - M);
    }
    __syncthreads();
  }
  if (tid == 0) partial[blockIdx.x] = make_float2(rm[0], rs[0]);

  unsigned short* out = hp + (size_t)blockIdx.x * NBINS;
  for (int i = tid; i < NBINS; i += 256) out[i] = (unsigned short)lh[i];

  // ---- ticket: last block of batch b becomes the threshold finisher ----
  __syncthreads();
  if (tid == 0) {
    __threadfence();                       // hp/partial visible device-wide
    unsigned r = atomicAdd(&tick[b], 1u);
    fin = (r == 15u);
  }
  __syncthreads();
  if (!fin) return;
  __threadfence();                         // acquire others' writes

  // sum the 16 private hists into lh (coalesced uint loads = 2 bins)
  for (int i = tid; i < NBINS / 2; i += 256) {
    unsigned s0 = 0, s1 = 0;
#pragma unroll
    for (int c = 0; c < 16; ++c) {
      unsigned u = *(const unsigned*)&hp[(size_t)(b * 16 + c) * NBINS + i * 2];
      s0 += u & 0xFFFFu; s1 += u >> 16;
    }
    lh[i * 2] = s0; lh[i * 2 + 1] = s1;
  }
  __shared__ float red_m, red_s;
  __shared__ unsigned cs[256];
  if (tid == 0) {
    float mm = -INFINITY, ss = 0.f;
    for (int i = 0; i < 16; ++i) {
      float2 p = partial[b * 16 + i];
      float M = fmaxf(mm, p.x);
      ss = ss * expf(mm - M) + p.y * expf(p.x - M);
      mm = M;
    }
    red_m = mm; red_s = ss;
  }
  __syncthreads();

  // strip scan from the top: thread t owns ranks [t*64, t*64+64)
  unsigned lsum = 0;
  for (int q = 0; q < 64; ++q) lsum += lh[NBINS - 1 - (tid * 64 + q)];
  cs[tid] = lsum;
  __syncthreads();
  for (int off = 1; off < 256; off <<= 1) {
    unsigned t = (tid >= off) ? cs[tid - off] : 0u;
    __syncthreads();
    cs[tid] += t;
    __syncthreads();
  }
  unsigned incl = cs[tid], excl = incl - lsum;
  if (excl < NPOST && incl >= NPOST) {
    unsigned running = excl;
    for (int q = 0; q < 64; ++q) {
      unsigned bin = NBINS - 1 - (tid * 64 + q);
      unsigned c = lh[bin];
      if (running < NPOST && running + c >= NPOST)
        meta[b] = make_float4(red_m, red_s, __uint_as_float(bin), 0.f);
      running += c;
    }
  }
}

// ---------------- K2: compact + presort segment (first 28 bitonic passes) ----
__global__ __launch_bounds__(256) void k_compact(const float* __restrict__ labels,
                                                 const float4* __restrict__ meta,
                                                 ull* __restrict__ cand) {
  int b = blockIdx.x >> 4, blk = blockIdx.x & 15;
  unsigned tb = __float_as_uint(meta[b].z);
  const int chunk = NA / 16;               // 9216 floats = 2304 float4
  const float4* row4 = (const float4*)(labels + (size_t)b * NA + blk * chunk);
  int tid = threadIdx.x;

  float4 v[9];
#pragma unroll
  for (int it = 0; it < 9; ++it)
    v[it] = row4[it * 256 + tid];

  unsigned c = 0;
#pragma unroll
  for (int it = 0; it < 9; ++it) {
    c += ((mkey(v[it].x) >> 18) >= tb);
    c += ((mkey(v[it].y) >> 18) >= tb);
    c += ((mkey(v[it].z) >> 18) >= tb);
    c += ((mkey(v[it].w) >> 18) >= tb);
  }

  __shared__ unsigned ssum[256];
  __shared__ ull seg[SEG];
  if (tid < SEG) seg[tid] = 0ULL;
  ssum[tid] = c;
  __syncthreads();
  for (int off = 1; off < 256; off <<= 1) {
    unsigned t = (tid >= off) ? ssum[tid - off] : 0u;
    __syncthreads();
    ssum[tid] += t;
    __syncthreads();
  }
  unsigned pos = ssum[tid] - c;            // exclusive prefix

  if (c) {
#pragma unroll
    for (int it = 0; it < 9; ++it) {
      float vals[4] = {v[it].x, v[it].y, v[it].z, v[it].w};
#pragma unroll
      for (int j = 0; j < 4; ++j) {
        unsigned kk = mkey(vals[j]);
        if ((kk >> 18) >= tb) {
          unsigned idx = (unsigned)(blk * chunk + (it * 256 + tid) * 4 + j);
          if (pos < SEG) seg[pos] = ((ull)kk << 32) | (unsigned)~idx;
          pos++;
        }
      }
    }
  }
  __syncthreads();

  // bitonic stages k=2..128 within the segment (descending run)
  for (int k = 2; k <= SEG; k <<= 1) {
    for (int j = k >> 1; j > 0; j >>= 1) {
      if (tid < SEG) {
        int e = tid, x = e ^ j;
        if (x > e) {
          ull a = seg[e], cc = seg[x];
          bool up = (e & k) == 0;
          if (up ? (a < cc) : (a > cc)) { seg[e] = cc; seg[x] = a; }
        }
      }
      __syncthreads();
    }
  }

  ull* cb = cand + (size_t)b * CAND_CAP + blk * SEG;
  if (tid < SEG) cb[tid] = seg[tid];
}

// ---------------- K3: exact rank via binary search in 16 sorted runs ---------
__global__ __launch_bounds__(512) void k_rank_emit(const ull* __restrict__ cand,
                                                   const float4* __restrict__ meta,
                                                   const float* __restrict__ labels,
                                                   const float* __restrict__ deltas,
                                                   const float4* __restrict__ anchors,
                                                   const float* __restrict__ variances,
                                                   float4* __restrict__ sboxes,
                                                   float* __restrict__ sscores) {
  int b = blockIdx.x >> 2, part = blockIdx.x & 3;
  __shared__ ull sd[CAND_CAP];
  for (int i = threadIdx.x; i < CAND_CAP; i += 512)
    sd[i] = cand[(size_t)b * CAND_CAP + i];  // 16 sorted (desc) 128-runs
  __syncthreads();

  ull x = sd[part * 512 + threadIdx.x];
  if (x == 0ULL) return;                     // zero-pad: rank >= 1000 anyway

  int rank = 0;
#pragma unroll
  for (int t = 0; t < 16; ++t) {
    const ull* run = &sd[t << 7];
    int p = 0;
    if (run[p + 63] > x) p += 64;
    if (run[p + 31] > x) p += 32;
    if (run[p + 15] > x) p += 16;
    if (run[p + 7]  > x) p += 8;
    if (run[p + 3]  > x) p += 4;
    if (run[p + 1]  > x) p += 2;
    if (run[p]      > x) p += 1;
    rank += p;
  }
  if (rank >= NPOST) return;

  unsigned idx = ~(unsigned)(x & 0xFFFFFFFFu);
  float4 mt = meta[b];
  float lab = labels[(size_t)b * NA + idx];
  float score = expf(lab - mt.x) / mt.y;

  float4 an = anchors[idx];                  // [y1,x1,y2,x2]
  float aw = an.w - an.y;
  float ah = an.z - an.x;
  float acx = an.y + 0.5f * aw;
  float acy = an.x + 0.5f * ah;
  float4 dl = *(const float4*)(deltas + ((size_t)b * NA + idx) * 4);
  float4 var = *(const float4*)variances;
  float t0 = dl.x * var.x, t1 = dl.y * var.y, t2 = dl.z * var.z, t3 = dl.w * var.w;
  float bw = expf(t3) * aw;
  float bh = expf(t2) * ah;
  float bcx = t1 * aw + acx;
  float bcy = t0 * ah + acy;
  float y1 = bcy - 0.5f * bh, x1 = bcx - 0.5f * bw;
  float y2 = bh + y1, x2 = bw + x1;
  sboxes[(size_t)b * NPOST + rank] = make_float4(y1, x1, y2, x2);
  sscores[(size_t)b * NPOST + rank] = score;
}

// ---------------- K4: IoU maskT + inline NMS finisher ------------------------
// 63 blocks per batch write lower-tri transposed mask tiles; the last block
// (ticket) runs the fully-unrolled ballot-chain NMS for its batch.
__global__ __launch_bounds__(256) void k_mask_nms(const float4* __restrict__ sboxes,
                                                  const float* __restrict__ sscores,
                                                  ull* __restrict__ maskT,
                                                  unsigned* __restrict__ tick,
                                                  float* __restrict__ out) {
  int b = blockIdx.x / 63, tile = blockIdx.x % 63;
  __shared__ float4 bx[NPOST];               // 16KB
  __shared__ int fin;
  int tid = threadIdx.x;
  for (int j = tid; j < NPOST; j += 256) bx[j] = sboxes[(size_t)b * NPOST + j];
  __syncthreads();
  {
    int il = tid >> 4, w = tid & 15;
    int i = tile * 16 + il;
    if (i < NPOST) {
      float4 bi = bx[i];
      float ay1 = bi.x, ax1 = bi.y, ay2 = bi.z, ax2 = bi.w;
      float areai = (ay2 - ay1) * (ax2 - ax1);
      ull bits = 0;
      for (int jj = 0; jj < 64; ++jj) {
        int jb = (jj + w) & 63;              // skew to dodge LDS bank conflicts
        int j = (w << 6) + jb;
        if (j < i) {                         // lower-tri: rows j that suppress col i
          float4 bj = bx[j];
          float areaj = (bj.z - bj.x) * (bj.w - bj.y);
          float iy1 = fmaxf(ay1, bj.x), ix1 = fmaxf(ax1, bj.y);
          float iy2 = fminf(ay2, bj.z), ix2 = fminf(ax2, bj.w);
          float inter = fmaxf(iy2 - iy1, 0.f) * fmaxf(ix2 - ix1, 0.f);
          float uni = areai + areaj - inter;
          float iou = inter / fmaxf(uni, 1e-9f);
          if (iou > 0.7f) bits |= (1ull << jb);
        }
      }
      maskT[((size_t)b * NPOST + i) * 16 + w] = bits;
    }
  }

  // ---- ticket: last block of batch b runs the NMS ----
  __syncthreads();
  if (tid == 0) {
    __threadfence();
    unsigned r = atomicAdd(&tick[b], 1u);
    fin = (r == 62u);
  }
  __syncthreads();
  if (!fin) return;
  __threadfence();

  __shared__ ull keep_lds[16];
  __shared__ int pref[17];

  if (tid < 64) {
    int lane = tid;
    const ull* MT = maskT + (size_t)b * NPOST * 16;

    ull colw[16], coln[16], ks[16];
#pragma unroll
    for (int k = 0; k < 16; ++k) { colw[k] = 0; coln[k] = 0; ks[k] = 0; }
    colw[0] = MT[(size_t)lane * 16 + 0];

#pragma unroll
    for (int w = 0; w < 16; ++w) {
      if (w < 15) {
        int nr = (w + 1) * 64 + lane; if (nr > NPOST - 1) nr = NPOST - 1;
#pragma unroll
        for (int k = 0; k < 16; ++k)
          if (k <= w + 1) coln[k] = MT[(size_t)nr * 16 + k];
      }

      ull acc = 0;
#pragma unroll
      for (int k = 0; k < 16; ++k)
        if (k < w) acc |= colw[k] & ks[k];
      ull rm0 = (w == 0) ? 0ull : __ballot(acc != 0ull);

      unsigned qlo = (unsigned)colw[w], qhi = (unsigned)(colw[w] >> 32);

      ull kmask = 0, supp = rm0;
#pragma unroll
      for (int bt = 0; bt < 4; ++bt) {
        ull rows[16];
        unsigned qd = (bt < 2) ? qlo : qhi;
#pragma unroll
        for (int r = 0; r < 16; ++r)
          rows[r] = __ballot(((qd >> ((bt & 1) * 16 + r)) & 1u) != 0u);
#pragma unroll
        for (int r = 0; r < 16; ++r) {
          int rr = bt * 16 + r;
          bool kp = ((supp >> rr) & 1ull) == 0ull;
          kmask |= kp ? (1ull << rr) : 0ull;
          supp  |= kp ? rows[r] : 0ull;
        }
      }
      if (w == 15) kmask &= (1ull << 40) - 1;   // boxes 1000..1023 invalid
      ks[w] = kmask;
      if (lane == 0) keep_lds[w] = kmask;

#pragma unroll
      for (int k = 0; k < 16; ++k) colw[k] = coln[k];
    }

    if (lane == 0) {
      int a = 0;
      for (int w = 0; w < 16; ++w) { pref[w] = a; a += __popcll(keep_lds[w]); }
      pref[16] = a;
    }
  }
  __syncthreads();

  int total = pref[16];
  float4* ob = (float4*)out;                 // boxes: 16*1000 float4
  float* os = out + (size_t)NB * NPOST * 4;  // scores: 16*1000 floats
  for (int r = tid; r < NPOST; r += 256) {
    if (r >= total) {
      ob[(size_t)b * NPOST + r] = make_float4(0.f, 0.f, 0.f, 0.f);
      os[(size_t)b * NPOST + r] = 0.f;
    }
  }
  for (int r = tid; r < NPOST; r += 256) {
    int w = r >> 6, bb = r & 63;
    ull kw = keep_lds[w];
    if ((kw >> bb) & 1ull) {
      int pos = pref[w] + __popcll(bb ? (kw & ((1ull << bb) - 1)) : 0ull);
      ob[(size_t)b * NPOST + pos] = sboxes[(size_t)b * NPOST + r];
      os[(size_t)b * NPOST + pos] = sscores[(size_t)b * NPOST + r];
    }
  }
}

extern "C" void kernel_launch(void* const* d_in, const int* in_sizes, int n_in,
                              void* d_out, int out_size, void* d_ws, size_t ws_size,
                              hipStream_t stream) {
  const float* deltas    = (const float*)d_in[0];
  const float* labels    = (const float*)d_in[1];
  const float* anchors   = (const float*)d_in[2];
  const float* variances = (const float*)d_in[3];

  char* ws = (char*)d_ws;
  ull*            cand    = (ull*)(ws + OFF_CAND);
  ull*            maskT   = (ull*)(ws + OFF_MASK);
  unsigned short* hp      = (unsigned short*)(ws + OFF_HP);
  float2*         partial = (float2*)(ws + OFF_PART);
  float4*         meta    = (float4*)(ws + OFF_META);
  float4*         sboxes  = (float4*)(ws + OFF_SBOX);
  float*          sscores = (float*)(ws + OFF_SSCORE);
  unsigned*       tickH   = (unsigned*)(ws + OFF_TICK);
  unsigned*       tickM   = (unsigned*)(ws + OFF_TICK + 64);

  hipMemsetAsync(ws + OFF_TICK, 0, 128, stream);   // zero tickets every call
  k_reduce_hist<<<NB * 16, 256, 0, stream>>>(labels, hp, partial, tickH, meta);
  k_compact<<<NB * 16, 256, 0, stream>>>(labels, meta, cand);
  k_rank_emit<<<NB * 4, 512, 0, stream>>>(cand, meta, labels, deltas,
                                          (const float4*)anchors, variances,
                                          sboxes, sscores);
  k_mask_nms<<<NB * 63, 256, 0, stream>>>(sboxes, sscores, maskT, tickM,
                                          (float*)d_out);
}

// Round 13
// 114.168 us; speedup vs baseline: 1.1731x; 1.1731x over previous
//
#include <hip/hip_runtime.h>

typedef unsigned long long ull;

#define NA 147456
#define NB 16
#define NBINS 16384        // top-14 bits of monotonic key
#define CAND_CAP 2048
#define SEG 128            // CAND_CAP / 16 chunks
#define NPOST 1000

// ws layout (bytes)  (ws is ~268 MB)
#define OFF_CAND    0                    // 16*2048*8       = 262144
#define OFF_MASK    262144               // 16*1000*16*8    = 2048000 (maskT)
#define OFF_HP      2310144              // 256*16384*2     = 8388608 (private u16 hists)
#define OFF_PART    10698752             // 256*8           = 2048
#define OFF_META    10700800             // 16*16           = 256
#define OFF_SBOX    10701056             // 16*1000*16      = 256000
#define OFF_SSCORE  10957056             // 16*1000*4       = 64000
#define OFF_TICK    11021312             // 16*4            = 64 (zeroed each call)

__device__ __forceinline__ unsigned mkey(float f) {
  unsigned u = __float_as_uint(f);
  return u ^ ((unsigned)((int)u >> 31) | 0x80000000u);  // monotonic: bigger float -> bigger key
}

// ---------------- K1: softmax-reduce + private hist + inline threshold -------
// 256 blocks; the 16th block to finish a batch (ticket) sums the 16 private
// hists and computes (m, S, threshold bin) -> meta[b]. No separate launch.
__global__ __launch_bounds__(256) void k_reduce_hist(const float* __restrict__ labels,
                                                     unsigned short* __restrict__ hp,
                                                     float2* __restrict__ partial,
                                                     unsigned* __restrict__ tick,
                                                     float4* __restrict__ meta) {
  int b = blockIdx.x >> 4, blk = blockIdx.x & 15;
  __shared__ unsigned lh[NBINS];           // 64KB
  __shared__ float rm[256], rs[256];
  __shared__ int fin;
  int tid = threadIdx.x;
  for (int i = tid; i < NBINS; i += 256) lh[i] = 0;
  __syncthreads();

  const int chunk = NA / 16;               // 9216 floats = 2304 float4
  const float4* row4 = (const float4*)(labels + (size_t)b * NA + blk * chunk);

  float4 v[9];
#pragma unroll
  for (int it = 0; it < 9; ++it)
    v[it] = row4[it * 256 + tid];

#pragma unroll
  for (int it = 0; it < 9; ++it) {
    atomicAdd(&lh[mkey(v[it].x) >> 18], 1u);
    atomicAdd(&lh[mkey(v[it].y) >> 18], 1u);
    atomicAdd(&lh[mkey(v[it].z) >> 18], 1u);
    atomicAdd(&lh[mkey(v[it].w) >> 18], 1u);
  }

  float m = -INFINITY;
#pragma unroll
  for (int it = 0; it < 9; ++it)
    m = fmaxf(m, fmaxf(fmaxf(v[it].x, v[it].y), fmaxf(v[it].z, v[it].w)));
  float s = 0.f;
#pragma unroll
  for (int it = 0; it < 9; ++it) {
    s += expf(v[it].x - m); s += expf(v[it].y - m);
    s += expf(v[it].z - m); s += expf(v[it].w - m);
  }

  rm[tid] = m; rs[tid] = s;
  __syncthreads();
  for (int off = 128; off > 0; off >>= 1) {
    if (tid < off) {
      float m1 = rm[tid], s1 = rs[tid];
      float m2 = rm[tid + off], s2 = rs[tid + off];
      float M = fmaxf(m1, m2);
      rm[tid] = M;
      rs[tid] = s1 * expf(m1 - M) + s2 * expf(m2 - M);
    }
    __syncthreads();
  }
  if (tid == 0) partial[blockIdx.x] = make_float2(rm[0], rs[0]);

  unsigned short* out = hp + (size_t)blockIdx.x * NBINS;
  for (int i = tid; i < NBINS; i += 256) out[i] = (unsigned short)lh[i];

  // ---- ticket: last block of batch b becomes the threshold finisher ----
  __syncthreads();
  if (tid == 0) {
    __threadfence();                       // hp/partial visible device-wide
    unsigned r = atomicAdd(&tick[b], 1u);
    fin = (r == 15u);
  }
  __syncthreads();
  if (!fin) return;
  __threadfence();                         // acquire others' writes

  // sum the 16 private hists into lh (coalesced uint loads = 2 bins)
  for (int i = tid; i < NBINS / 2; i += 256) {
    unsigned s0 = 0, s1 = 0;
#pragma unroll
    for (int c = 0; c < 16; ++c) {
      unsigned u = *(const unsigned*)&hp[(size_t)(b * 16 + c) * NBINS + i * 2];
      s0 += u & 0xFFFFu; s1 += u >> 16;
    }
    lh[i * 2] = s0; lh[i * 2 + 1] = s1;
  }
  __shared__ float red_m, red_s;
  __shared__ unsigned cs[256];
  if (tid == 0) {
    float mm = -INFINITY, ss = 0.f;
    for (int i = 0; i < 16; ++i) {
      float2 p = partial[b * 16 + i];
      float M = fmaxf(mm, p.x);
      ss = ss * expf(mm - M) + p.y * expf(p.x - M);
      mm = M;
    }
    red_m = mm; red_s = ss;
  }
  __syncthreads();

  // strip scan from the top: thread t owns ranks [t*64, t*64+64)
  unsigned lsum = 0;
  for (int q = 0; q < 64; ++q) lsum += lh[NBINS - 1 - (tid * 64 + q)];
  cs[tid] = lsum;
  __syncthreads();
  for (int off = 1; off < 256; off <<= 1) {
    unsigned t = (tid >= off) ? cs[tid - off] : 0u;
    __syncthreads();
    cs[tid] += t;
    __syncthreads();
  }
  unsigned incl = cs[tid], excl = incl - lsum;
  if (excl < NPOST && incl >= NPOST) {
    unsigned running = excl;
    for (int q = 0; q < 64; ++q) {
      unsigned bin = NBINS - 1 - (tid * 64 + q);
      unsigned c = lh[bin];
      if (running < NPOST && running + c >= NPOST)
        meta[b] = make_float4(red_m, red_s, __uint_as_float(bin), 0.f);
      running += c;
    }
  }
}

// ---------------- K2: compact + presort segment (first 28 bitonic passes) ----
__global__ __launch_bounds__(256) void k_compact(const float* __restrict__ labels,
                                                 const float4* __restrict__ meta,
                                                 ull* __restrict__ cand) {
  int b = blockIdx.x >> 4, blk = blockIdx.x & 15;
  unsigned tb = __float_as_uint(meta[b].z);
  const int chunk = NA / 16;               // 9216 floats = 2304 float4
  const float4* row4 = (const float4*)(labels + (size_t)b * NA + blk * chunk);
  int tid = threadIdx.x;

  float4 v[9];
#pragma unroll
  for (int it = 0; it < 9; ++it)
    v[it] = row4[it * 256 + tid];

  unsigned c = 0;
#pragma unroll
  for (int it = 0; it < 9; ++it) {
    c += ((mkey(v[it].x) >> 18) >= tb);
    c += ((mkey(v[it].y) >> 18) >= tb);
    c += ((mkey(v[it].z) >> 18) >= tb);
    c += ((mkey(v[it].w) >> 18) >= tb);
  }

  __shared__ unsigned ssum[256];
  __shared__ ull seg[SEG];
  if (tid < SEG) seg[tid] = 0ULL;
  ssum[tid] = c;
  __syncthreads();
  for (int off = 1; off < 256; off <<= 1) {
    unsigned t = (tid >= off) ? ssum[tid - off] : 0u;
    __syncthreads();
    ssum[tid] += t;
    __syncthreads();
  }
  unsigned pos = ssum[tid] - c;            // exclusive prefix

  if (c) {
#pragma unroll
    for (int it = 0; it < 9; ++it) {
      float vals[4] = {v[it].x, v[it].y, v[it].z, v[it].w};
#pragma unroll
      for (int j = 0; j < 4; ++j) {
        unsigned kk = mkey(vals[j]);
        if ((kk >> 18) >= tb) {
          unsigned idx = (unsigned)(blk * chunk + (it * 256 + tid) * 4 + j);
          if (pos < SEG) seg[pos] = ((ull)kk << 32) | (unsigned)~idx;
          pos++;
        }
      }
    }
  }
  __syncthreads();

  // bitonic stages k=2..128 within the segment (descending run)
  for (int k = 2; k <= SEG; k <<= 1) {
    for (int j = k >> 1; j > 0; j >>= 1) {
      if (tid < SEG) {
        int e = tid, x = e ^ j;
        if (x > e) {
          ull a = seg[e], cc = seg[x];
          bool up = (e & k) == 0;
          if (up ? (a < cc) : (a > cc)) { seg[e] = cc; seg[x] = a; }
        }
      }
      __syncthreads();
    }
  }

  ull* cb = cand + (size_t)b * CAND_CAP + blk * SEG;
  if (tid < SEG) cb[tid] = seg[tid];
}

// ---------------- K3: exact rank via binary search in 16 sorted runs ---------
__global__ __launch_bounds__(512) void k_rank_emit(const ull* __restrict__ cand,
                                                   const float4* __restrict__ meta,
                                                   const float* __restrict__ labels,
                                                   const float* __restrict__ deltas,
                                                   const float4* __restrict__ anchors,
                                                   const float* __restrict__ variances,
                                                   float4* __restrict__ sboxes,
                                                   float* __restrict__ sscores) {
  int b = blockIdx.x >> 2, part = blockIdx.x & 3;
  __shared__ ull sd[CAND_CAP];
  for (int i = threadIdx.x; i < CAND_CAP; i += 512)
    sd[i] = cand[(size_t)b * CAND_CAP + i];  // 16 sorted (desc) 128-runs
  __syncthreads();

  ull x = sd[part * 512 + threadIdx.x];
  if (x == 0ULL) return;                     // zero-pad: rank >= 1000 anyway

  int rank = 0;
#pragma unroll
  for (int t = 0; t < 16; ++t) {
    const ull* run = &sd[t << 7];
    int p = 0;
    if (run[p + 63] > x) p += 64;
    if (run[p + 31] > x) p += 32;
    if (run[p + 15] > x) p += 16;
    if (run[p + 7]  > x) p += 8;
    if (run[p + 3]  > x) p += 4;
    if (run[p + 1]  > x) p += 2;
    if (run[p]      > x) p += 1;
    rank += p;
  }
  if (rank >= NPOST) return;

  unsigned idx = ~(unsigned)(x & 0xFFFFFFFFu);
  float4 mt = meta[b];
  float lab = labels[(size_t)b * NA + idx];
  float score = expf(lab - mt.x) / mt.y;

  float4 an = anchors[idx];                  // [y1,x1,y2,x2]
  float aw = an.w - an.y;
  float ah = an.z - an.x;
  float acx = an.y + 0.5f * aw;
  float acy = an.x + 0.5f * ah;
  float4 dl = *(const float4*)(deltas + ((size_t)b * NA + idx) * 4);
  float4 var = *(const float4*)variances;
  float t0 = dl.x * var.x, t1 = dl.y * var.y, t2 = dl.z * var.z, t3 = dl.w * var.w;
  float bw = expf(t3) * aw;
  float bh = expf(t2) * ah;
  float bcx = t1 * aw + acx;
  float bcy = t0 * ah + acy;
  float y1 = bcy - 0.5f * bh, x1 = bcx - 0.5f * bw;
  float y2 = bh + y1, x2 = bw + x1;
  sboxes[(size_t)b * NPOST + rank] = make_float4(y1, x1, y2, x2);
  sscores[(size_t)b * NPOST + rank] = score;
}

// ---------------- K4: pairwise IoU, TRANSPOSED (lower-tri) bitmask -----------
__global__ __launch_bounds__(256) void k_mask(const float4* __restrict__ sboxes,
                                              ull* __restrict__ maskT) {
  int b = blockIdx.x / 63, tile = blockIdx.x % 63;
  __shared__ float4 bx[NPOST];               // 16KB
  for (int j = threadIdx.x; j < NPOST; j += 256) bx[j] = sboxes[(size_t)b * NPOST + j];
  __syncthreads();
  int il = threadIdx.x >> 4, w = threadIdx.x & 15;
  int i = tile * 16 + il;
  if (i < NPOST) {
    float4 bi = bx[i];
    float ay1 = bi.x, ax1 = bi.y, ay2 = bi.z, ax2 = bi.w;
    float areai = (ay2 - ay1) * (ax2 - ax1);
    ull bits = 0;
    for (int jj = 0; jj < 64; ++jj) {
      int jb = (jj + w) & 63;                // skew to dodge LDS bank conflicts
      int j = (w << 6) + jb;
      if (j < i) {                           // lower-tri: rows j that suppress col i
        float4 bj = bx[j];
        float areaj = (bj.z - bj.x) * (bj.w - bj.y);
        float iy1 = fmaxf(ay1, bj.x), ix1 = fmaxf(ax1, bj.y);
        float iy2 = fminf(ay2, bj.z), ix2 = fminf(ax2, bj.w);
        float inter = fmaxf(iy2 - iy1, 0.f) * fmaxf(ix2 - ix1, 0.f);
        float uni = areai + areaj - inter;
        float iou = inter / fmaxf(uni, 1e-9f);
        if (iou > 0.7f) bits |= (1ull << jb);
      }
    }
    maskT[((size_t)b * NPOST + i) * 16 + w] = bits;
  }
}

// ---------------- K5: greedy NMS, fully unrolled, ballot-row chain -----------
__global__ __launch_bounds__(256, 1) void k_nms(const ull* __restrict__ maskT,
                                                const float4* __restrict__ sboxes,
                                                const float* __restrict__ sscores,
                                                float* __restrict__ out) {
  int b = blockIdx.x;
  __shared__ ull keep_lds[16];
  __shared__ int pref[17];
  int tid = threadIdx.x;

  if (tid < 64) {
    int lane = tid;
    const ull* MT = maskT + (size_t)b * NPOST * 16;

    ull colw[16], coln[16], ks[16];
#pragma unroll
    for (int k = 0; k < 16; ++k) { colw[k] = 0; coln[k] = 0; ks[k] = 0; }
    colw[0] = MT[(size_t)lane * 16 + 0];

#pragma unroll
    for (int w = 0; w < 16; ++w) {
      if (w < 15) {
        int nr = (w + 1) * 64 + lane; if (nr > NPOST - 1) nr = NPOST - 1;
#pragma unroll
        for (int k = 0; k < 16; ++k)
          if (k <= w + 1) coln[k] = MT[(size_t)nr * 16 + k];
      }

      ull acc = 0;
#pragma unroll
      for (int k = 0; k < 16; ++k)
        if (k < w) acc |= colw[k] & ks[k];
      ull rm0 = (w == 0) ? 0ull : __ballot(acc != 0ull);

      unsigned qlo = (unsigned)colw[w], qhi = (unsigned)(colw[w] >> 32);

      ull kmask = 0, supp = rm0;
#pragma unroll
      for (int bt = 0; bt < 4; ++bt) {
        ull rows[16];
        unsigned qd = (bt < 2) ? qlo : qhi;
#pragma unroll
        for (int r = 0; r < 16; ++r)
          rows[r] = __ballot(((qd >> ((bt & 1) * 16 + r)) & 1u) != 0u);
#pragma unroll
        for (int r = 0; r < 16; ++r) {
          int rr = bt * 16 + r;
          bool kp = ((supp >> rr) & 1ull) == 0ull;
          kmask |= kp ? (1ull << rr) : 0ull;
          supp  |= kp ? rows[r] : 0ull;
        }
      }
      if (w == 15) kmask &= (1ull << 40) - 1;   // boxes 1000..1023 invalid
      ks[w] = kmask;
      if (lane == 0) keep_lds[w] = kmask;

#pragma unroll
      for (int k = 0; k < 16; ++k) colw[k] = coln[k];
    }

    if (lane == 0) {
      int a = 0;
      for (int w = 0; w < 16; ++w) { pref[w] = a; a += __popcll(keep_lds[w]); }
      pref[16] = a;
    }
  }
  __syncthreads();

  int total = pref[16];
  float4* ob = (float4*)out;                 // boxes: 16*1000 float4
  float* os = out + (size_t)NB * NPOST * 4;  // scores: 16*1000 floats
  for (int r = tid; r < NPOST; r += 256) {
    if (r >= total) {
      ob[(size_t)b * NPOST + r] = make_float4(0.f, 0.f, 0.f, 0.f);
      os[(size_t)b * NPOST + r] = 0.f;
    }
  }
  for (int r = tid; r < NPOST; r += 256) {
    int w = r >> 6, bb = r & 63;
    ull kw = keep_lds[w];
    if ((kw >> bb) & 1ull) {
      int pos = pref[w] + __popcll(bb ? (kw & ((1ull << bb) - 1)) : 0ull);
      ob[(size_t)b * NPOST + pos] = sboxes[(size_t)b * NPOST + r];
      os[(size_t)b * NPOST + pos] = sscores[(size_t)b * NPOST + r];
    }
  }
}

extern "C" void kernel_launch(void* const* d_in, const int* in_sizes, int n_in,
                              void* d_out, int out_size, void* d_ws, size_t ws_size,
                              hipStream_t stream) {
  const float* deltas    = (const float*)d_in[0];
  const float* labels    = (const float*)d_in[1];
  const float* anchors   = (const float*)d_in[2];
  const float* variances = (const float*)d_in[3];

  char* ws = (char*)d_ws;
  ull*            cand    = (ull*)(ws + OFF_CAND);
  ull*            maskT   = (ull*)(ws + OFF_MASK);
  unsigned short* hp      = (unsigned short*)(ws + OFF_HP);
  float2*         partial = (float2*)(ws + OFF_PART);
  float4*         meta    = (float4*)(ws + OFF_META);
  float4*         sboxes  = (float4*)(ws + OFF_SBOX);
  float*          sscores = (float*)(ws + OFF_SSCORE);
  unsigned*       tickH   = (unsigned*)(ws + OFF_TICK);

  hipMemsetAsync(ws + OFF_TICK, 0, 64, stream);    // zero tickets every call
  k_reduce_hist<<<NB * 16, 256, 0, stream>>>(labels, hp, partial, tickH, meta);
  k_compact<<<NB * 16, 256, 0, stream>>>(labels, meta, cand);
  k_rank_emit<<<NB * 4, 512, 0, stream>>>(cand, meta, labels, deltas,
                                          (const float4*)anchors, variances,
                                          sboxes, sscores);
  k_mask<<<NB * 63, 256, 0, stream>>>(sboxes, maskT);
  k_nms<<<NB, 256, 0, stream>>>(maskT, sboxes, sscores, (float*)d_out);
}

// Round 14
// 102.036 us; speedup vs baseline: 1.3126x; 1.1189x over previous
//
#include <hip/hip_runtime.h>

typedef unsigned long long ull;

#define NA 147456
#define NB 16
#define NBINS 16384        // top-14 bits of monotonic key
#define CAND_CAP 2048
#define SEG 128            // CAND_CAP / 16 chunks
#define NPOST 1000
#define HB 48              // hist blocks per batch
#define HCHUNK (NA / HB)   // 3072 floats = 768 float4

// ws layout (bytes)  (ws is ~268 MB)
#define OFF_CAND    0                    // 16*2048*8        = 262144
#define OFF_MASK    262144               // 16*1000*16*8     = 2048000 (maskT)
#define OFF_HP      2310144              // 768*8192*4       = 25165824 (packed 2xu16)
#define OFF_PART    27475968             // 768*8            = 6144
#define OFF_META    27482112             // 16*16            = 256
#define OFF_SBOX    27482368             // 16*1000*16       = 256000
#define OFF_SSCORE  27738368             // 16*1000*4        = 64000

__device__ __forceinline__ unsigned mkey(float f) {
  unsigned u = __float_as_uint(f);
  return u ^ ((unsigned)((int)u >> 31) | 0x80000000u);  // monotonic: bigger float -> bigger key
}

// ---------------- K1: softmax-reduce + packed private histogram --------------
// 48 blocks/batch (~3 blocks/CU), 32KB packed LDS hist (2 u16 bins per u32
// word) -> 4 blocks/CU residency. No global atomics; no fences (kernel
// boundary provides release -- R13 lesson: in-kernel __threadfence costs
// a per-block L2 writeback).
__global__ __launch_bounds__(256) void k_reduce_hist(const float* __restrict__ labels,
                                                     unsigned* __restrict__ hp,
                                                     float2* __restrict__ partial) {
  int b = blockIdx.x / HB, blk = blockIdx.x % HB;
  __shared__ unsigned lh[NBINS / 2];       // 32KB packed
  __shared__ float rm[256], rs[256];
  int tid = threadIdx.x;
  for (int i = tid; i < NBINS / 2; i += 256) lh[i] = 0;
  __syncthreads();

  const float4* row4 = (const float4*)(labels + (size_t)b * NA + blk * HCHUNK);

  float4 v[3];
#pragma unroll
  for (int it = 0; it < 3; ++it)
    v[it] = row4[it * 256 + tid];

#pragma unroll
  for (int it = 0; it < 3; ++it) {
    float vals[4] = {v[it].x, v[it].y, v[it].z, v[it].w};
#pragma unroll
    for (int j = 0; j < 4; ++j) {
      unsigned k = mkey(vals[j]) >> 18;
      atomicAdd(&lh[k >> 1], (k & 1u) ? 65536u : 1u);
    }
  }

  float m = -INFINITY;
#pragma unroll
  for (int it = 0; it < 3; ++it)
    m = fmaxf(m, fmaxf(fmaxf(v[it].x, v[it].y), fmaxf(v[it].z, v[it].w)));
  float s = 0.f;
#pragma unroll
  for (int it = 0; it < 3; ++it) {
    s += expf(v[it].x - m); s += expf(v[it].y - m);
    s += expf(v[it].z - m); s += expf(v[it].w - m);
  }

  rm[tid] = m; rs[tid] = s;
  __syncthreads();
  for (int off = 128; off > 0; off >>= 1) {
    if (tid < off) {
      float m1 = rm[tid], s1 = rs[tid];
      float m2 = rm[tid + off], s2 = rs[tid + off];
      float M = fmaxf(m1, m2);
      rm[tid] = M;
      rs[tid] = s1 * expf(m1 - M) + s2 * expf(m2 - M);
    }
    __syncthreads();
  }
  if (tid == 0) partial[blockIdx.x] = make_float2(rm[0], rs[0]);

  unsigned* out = hp + (size_t)blockIdx.x * (NBINS / 2);
  for (int i = tid; i < NBINS / 2; i += 256) out[i] = lh[i];
}

// ---------------- K2: sum 48 packed hists, finalize (m,S), threshold bin -----
__global__ __launch_bounds__(1024) void k_threshold(const unsigned* __restrict__ hp,
                                                    const float2* __restrict__ partial,
                                                    float4* __restrict__ meta) {
  int b = blockIdx.x;
  __shared__ unsigned lh[NBINS];           // 64KB summed histogram
  __shared__ float red_m, red_s;
  __shared__ unsigned cs[1024];
  int t = threadIdx.x;

  for (int i = t; i < NBINS / 2; i += 1024) {
    unsigned s0 = 0, s1 = 0;
#pragma unroll 8
    for (int c = 0; c < HB; ++c) {
      unsigned u = hp[(size_t)(b * HB + c) * (NBINS / 2) + i];
      s0 += u & 0xFFFFu; s1 += u >> 16;
    }
    lh[i * 2] = s0; lh[i * 2 + 1] = s1;
  }
  if (t == 0) {
    float m = -INFINITY, s = 0.f;
    for (int i = 0; i < HB; ++i) {
      float2 p = partial[b * HB + i];
      float M = fmaxf(m, p.x);
      s = s * expf(m - M) + p.y * expf(p.x - M);
      m = M;
    }
    red_m = m; red_s = s;
  }
  __syncthreads();

  unsigned local[16], lsum = 0;
  for (int q = 0; q < 16; ++q) {            // rank r = t*16+q, bin = NBINS-1-r
    local[q] = lh[NBINS - 1 - (t * 16 + q)];
    lsum += local[q];
  }
  cs[t] = lsum;
  __syncthreads();
  for (int off = 1; off < 1024; off <<= 1) {  // Hillis-Steele inclusive scan
    unsigned v = (t >= off) ? cs[t - off] : 0u;
    __syncthreads();
    cs[t] += v;
    __syncthreads();
  }
  unsigned incl = cs[t], excl = incl - lsum;
  if (excl < NPOST && incl >= NPOST) {
    unsigned running = excl;
    for (int q = 0; q < 16; ++q) {
      unsigned c = local[q];
      if (running < NPOST && running + c >= NPOST) {
        unsigned bin = NBINS - 1 - (t * 16 + q);
        meta[b] = make_float4(red_m, red_s, __uint_as_float(bin), 0.f);
      }
      running += c;
    }
  }
}

// ---------------- K3: compact + presort segment (first 28 bitonic passes) ----
__global__ __launch_bounds__(256) void k_compact(const float* __restrict__ labels,
                                                 const float4* __restrict__ meta,
                                                 ull* __restrict__ cand) {
  int b = blockIdx.x >> 4, blk = blockIdx.x & 15;
  unsigned tb = __float_as_uint(meta[b].z);
  const int chunk = NA / 16;               // 9216 floats = 2304 float4
  const float4* row4 = (const float4*)(labels + (size_t)b * NA + blk * chunk);
  int tid = threadIdx.x;

  float4 v[9];
#pragma unroll
  for (int it = 0; it < 9; ++it)
    v[it] = row4[it * 256 + tid];

  unsigned c = 0;
#pragma unroll
  for (int it = 0; it < 9; ++it) {
    c += ((mkey(v[it].x) >> 18) >= tb);
    c += ((mkey(v[it].y) >> 18) >= tb);
    c += ((mkey(v[it].z) >> 18) >= tb);
    c += ((mkey(v[it].w) >> 18) >= tb);
  }

  __shared__ unsigned ssum[256];
  __shared__ ull seg[SEG];
  if (tid < SEG) seg[tid] = 0ULL;
  ssum[tid] = c;
  __syncthreads();
  for (int off = 1; off < 256; off <<= 1) {
    unsigned t = (tid >= off) ? ssum[tid - off] : 0u;
    __syncthreads();
    ssum[tid] += t;
    __syncthreads();
  }
  unsigned pos = ssum[tid] - c;            // exclusive prefix

  if (c) {
#pragma unroll
    for (int it = 0; it < 9; ++it) {
      float vals[4] = {v[it].x, v[it].y, v[it].z, v[it].w};
#pragma unroll
      for (int j = 0; j < 4; ++j) {
        unsigned kk = mkey(vals[j]);
        if ((kk >> 18) >= tb) {
          unsigned idx = (unsigned)(blk * chunk + (it * 256 + tid) * 4 + j);
          if (pos < SEG) seg[pos] = ((ull)kk << 32) | (unsigned)~idx;
          pos++;
        }
      }
    }
  }
  __syncthreads();

  // bitonic stages k=2..128 within the segment (descending run)
  for (int k = 2; k <= SEG; k <<= 1) {
    for (int j = k >> 1; j > 0; j >>= 1) {
      if (tid < SEG) {
        int e = tid, x = e ^ j;
        if (x > e) {
          ull a = seg[e], cc = seg[x];
          bool up = (e & k) == 0;
          if (up ? (a < cc) : (a > cc)) { seg[e] = cc; seg[x] = a; }
        }
      }
      __syncthreads();
    }
  }

  ull* cb = cand + (size_t)b * CAND_CAP + blk * SEG;
  if (tid < SEG) cb[tid] = seg[tid];
}

// ---------------- K4: exact rank via binary search in 16 sorted runs ---------
__global__ __launch_bounds__(512) void k_rank_emit(const ull* __restrict__ cand,
                                                   const float4* __restrict__ meta,
                                                   const float* __restrict__ labels,
                                                   const float* __restrict__ deltas,
                                                   const float4* __restrict__ anchors,
                                                   const float* __restrict__ variances,
                                                   float4* __restrict__ sboxes,
                                                   float* __restrict__ sscores) {
  int b = blockIdx.x >> 2, part = blockIdx.x & 3;
  __shared__ ull sd[CAND_CAP];
  for (int i = threadIdx.x; i < CAND_CAP; i += 512)
    sd[i] = cand[(size_t)b * CAND_CAP + i];  // 16 sorted (desc) 128-runs
  __syncthreads();

  ull x = sd[part * 512 + threadIdx.x];
  if (x == 0ULL) return;                     // zero-pad: rank >= 1000 anyway

  int rank = 0;
#pragma unroll
  for (int t = 0; t < 16; ++t) {
    const ull* run = &sd[t << 7];
    int p = 0;
    if (run[p + 63] > x) p += 64;
    if (run[p + 31] > x) p += 32;
    if (run[p + 15] > x) p += 16;
    if (run[p + 7]  > x) p += 8;
    if (run[p + 3]  > x) p += 4;
    if (run[p + 1]  > x) p += 2;
    if (run[p]      > x) p += 1;
    rank += p;
  }
  if (rank >= NPOST) return;

  unsigned idx = ~(unsigned)(x & 0xFFFFFFFFu);
  float4 mt = meta[b];
  float lab = labels[(size_t)b * NA + idx];
  float score = expf(lab - mt.x) / mt.y;

  float4 an = anchors[idx];                  // [y1,x1,y2,x2]
  float aw = an.w - an.y;
  float ah = an.z - an.x;
  float acx = an.y + 0.5f * aw;
  float acy = an.x + 0.5f * ah;
  float4 dl = *(const float4*)(deltas + ((size_t)b * NA + idx) * 4);
  float4 var = *(const float4*)variances;
  float t0 = dl.x * var.x, t1 = dl.y * var.y, t2 = dl.z * var.z, t3 = dl.w * var.w;
  float bw = expf(t3) * aw;
  float bh = expf(t2) * ah;
  float bcx = t1 * aw + acx;
  float bcy = t0 * ah + acy;
  float y1 = bcy - 0.5f * bh, x1 = bcx - 0.5f * bw;
  float y2 = bh + y1, x2 = bw + x1;
  sboxes[(size_t)b * NPOST + rank] = make_float4(y1, x1, y2, x2);
  sscores[(size_t)b * NPOST + rank] = score;
}

// ---------------- K5: pairwise IoU, TRANSPOSED (lower-tri) bitmask -----------
__global__ __launch_bounds__(256) void k_mask(const float4* __restrict__ sboxes,
                                              ull* __restrict__ maskT) {
  int b = blockIdx.x / 63, tile = blockIdx.x % 63;
  __shared__ float4 bx[NPOST];               // 16KB
  for (int j = threadIdx.x; j < NPOST; j += 256) bx[j] = sboxes[(size_t)b * NPOST + j];
  __syncthreads();
  int il = threadIdx.x >> 4, w = threadIdx.x & 15;
  int i = tile * 16 + il;
  if (i < NPOST) {
    float4 bi = bx[i];
    float ay1 = bi.x, ax1 = bi.y, ay2 = bi.z, ax2 = bi.w;
    float areai = (ay2 - ay1) * (ax2 - ax1);
    ull bits = 0;
    for (int jj = 0; jj < 64; ++jj) {
      int jb = (jj + w) & 63;                // skew to dodge LDS bank conflicts
      int j = (w << 6) + jb;
      if (j < i) {                           // lower-tri: rows j that suppress col i
        float4 bj = bx[j];
        float areaj = (bj.z - bj.x) * (bj.w - bj.y);
        float iy1 = fmaxf(ay1, bj.x), ix1 = fmaxf(ax1, bj.y);
        float iy2 = fminf(ay2, bj.z), ix2 = fminf(ax2, bj.w);
        float inter = fmaxf(iy2 - iy1, 0.f) * fmaxf(ix2 - ix1, 0.f);
        float uni = areai + areaj - inter;
        float iou = inter / fmaxf(uni, 1e-9f);
        if (iou > 0.7f) bits |= (1ull << jb);
      }
    }
    maskT[((size_t)b * NPOST + i) * 16 + w] = bits;
  }
}

// ---------------- K6: greedy NMS, fully unrolled, ballot-row chain -----------
__global__ __launch_bounds__(256, 1) void k_nms(const ull* __restrict__ maskT,
                                                const float4* __restrict__ sboxes,
                                                const float* __restrict__ sscores,
                                                float* __restrict__ out) {
  int b = blockIdx.x;
  __shared__ ull keep_lds[16];
  __shared__ int pref[17];
  int tid = threadIdx.x;

  if (tid < 64) {
    int lane = tid;
    const ull* MT = maskT + (size_t)b * NPOST * 16;

    ull colw[16], coln[16], ks[16];
#pragma unroll
    for (int k = 0; k < 16; ++k) { colw[k] = 0; coln[k] = 0; ks[k] = 0; }
    colw[0] = MT[(size_t)lane * 16 + 0];

#pragma unroll
    for (int w = 0; w < 16; ++w) {
      if (w < 15) {
        int nr = (w + 1) * 64 + lane; if (nr > NPOST - 1) nr = NPOST - 1;
#pragma unroll
        for (int k = 0; k < 16; ++k)
          if (k <= w + 1) coln[k] = MT[(size_t)nr * 16 + k];
      }

      ull acc = 0;
#pragma unroll
      for (int k = 0; k < 16; ++k)
        if (k < w) acc |= colw[k] & ks[k];
      ull rm0 = (w == 0) ? 0ull : __ballot(acc != 0ull);

      unsigned qlo = (unsigned)colw[w], qhi = (unsigned)(colw[w] >> 32);

      ull kmask = 0, supp = rm0;
#pragma unroll
      for (int bt = 0; bt < 4; ++bt) {
        ull rows[16];
        unsigned qd = (bt < 2) ? qlo : qhi;
#pragma unroll
        for (int r = 0; r < 16; ++r)
          rows[r] = __ballot(((qd >> ((bt & 1) * 16 + r)) & 1u) != 0u);
#pragma unroll
        for (int r = 0; r < 16; ++r) {
          int rr = bt * 16 + r;
          bool kp = ((supp >> rr) & 1ull) == 0ull;
          kmask |= kp ? (1ull << rr) : 0ull;
          supp  |= kp ? rows[r] : 0ull;
        }
      }
      if (w == 15) kmask &= (1ull << 40) - 1;   // boxes 1000..1023 invalid
      ks[w] = kmask;
      if (lane == 0) keep_lds[w] = kmask;

#pragma unroll
      for (int k = 0; k < 16; ++k) colw[k] = coln[k];
    }

    if (lane == 0) {
      int a = 0;
      for (int w = 0; w < 16; ++w) { pref[w] = a; a += __popcll(keep_lds[w]); }
      pref[16] = a;
    }
  }
  __syncthreads();

  int total = pref[16];
  float4* ob = (float4*)out;                 // boxes: 16*1000 float4
  float* os = out + (size_t)NB * NPOST * 4;  // scores: 16*1000 floats
  for (int r = tid; r < NPOST; r += 256) {
    if (r >= total) {
      ob[(size_t)b * NPOST + r] = make_float4(0.f, 0.f, 0.f, 0.f);
      os[(size_t)b * NPOST + r] = 0.f;
    }
  }
  for (int r = tid; r < NPOST; r += 256) {
    int w = r >> 6, bb = r & 63;
    ull kw = keep_lds[w];
    if ((kw >> bb) & 1ull) {
      int pos = pref[w] + __popcll(bb ? (kw & ((1ull << bb) - 1)) : 0ull);
      ob[(size_t)b * NPOST + pos] = sboxes[(size_t)b * NPOST + r];
      os[(size_t)b * NPOST + pos] = sscores[(size_t)b * NPOST + r];
    }
  }
}

extern "C" void kernel_launch(void* const* d_in, const int* in_sizes, int n_in,
                              void* d_out, int out_size, void* d_ws, size_t ws_size,
                              hipStream_t stream) {
  const float* deltas    = (const float*)d_in[0];
  const float* labels    = (const float*)d_in[1];
  const float* anchors   = (const float*)d_in[2];
  const float* variances = (const float*)d_in[3];

  char* ws = (char*)d_ws;
  ull*      cand    = (ull*)(ws + OFF_CAND);
  ull*      maskT   = (ull*)(ws + OFF_MASK);
  unsigned* hp      = (unsigned*)(ws + OFF_HP);
  float2*   partial = (float2*)(ws + OFF_PART);
  float4*   meta    = (float4*)(ws + OFF_META);
  float4*   sboxes  = (float4*)(ws + OFF_SBOX);
  float*    sscores = (float*)(ws + OFF_SSCORE);

  k_reduce_hist<<<NB * HB, 256, 0, stream>>>(labels, hp, partial);
  k_threshold<<<NB, 1024, 0, stream>>>(hp, partial, meta);
  k_compact<<<NB * 16, 256, 0, stream>>>(labels, meta, cand);
  k_rank_emit<<<NB * 4, 512, 0, stream>>>(cand, meta, labels, deltas,
                                          (const float4*)anchors, variances,
                                          sboxes, sscores);
  k_mask<<<NB * 63, 256, 0, stream>>>(sboxes, maskT);
  k_nms<<<NB, 256, 0, stream>>>(maskT, sboxes, sscores, (float*)d_out);
}

// Round 15
// 86.660 us; speedup vs baseline: 1.5455x; 1.1774x over previous
//
#include <hip/hip_runtime.h>

typedef unsigned long long ull;

#define NA 147456
#define NB 16
#define NBINS 16384        // top-14 bits of monotonic key
#define CAND_CAP 2048
#define SEG 128            // CAND_CAP / 16 chunks
#define NPOST 1000

// ws layout (bytes)  (ws is ~268 MB)
#define OFF_CAND    0                    // 16*2048*8       = 262144
#define OFF_MASK    262144               // 16*1000*16*8    = 2048000 (maskT)
#define OFF_HP      2310144              // 256*16384*2     = 8388608 (private u16 hists)
#define OFF_PART    10698752             // 256*8           = 2048
#define OFF_META    10700800             // 16*16           = 256
#define OFF_SBOX    10701056             // 16*1000*16      = 256000
#define OFF_SSCORE  10957056             // 16*1000*4       = 64000

__device__ __forceinline__ unsigned mkey(float f) {
  unsigned u = __float_as_uint(f);
  return u ^ ((unsigned)((int)u >> 31) | 0x80000000u);  // monotonic: bigger float -> bigger key
}

// ---------------- K1: fused softmax-reduce + private 14-bit histogram --------
// R11 structure (16 blocks/batch, u16 private copies), upgraded to 1024
// threads: 4 waves/SIMD instead of 1 -> latency hiding for the LDS-atomic
// + expf stream; LDS init/writeback 4x fewer iters per thread.
__global__ __launch_bounds__(1024) void k_reduce_hist(const float* __restrict__ labels,
                                                      unsigned short* __restrict__ hp,
                                                      float2* __restrict__ partial) {
  int b = blockIdx.x >> 4, blk = blockIdx.x & 15;
  __shared__ unsigned lh[NBINS];           // 64KB
  __shared__ float rm[1024], rs[1024];     // 8KB
  int tid = threadIdx.x;
  for (int i = tid; i < NBINS; i += 1024) lh[i] = 0;
  __syncthreads();

  const int chunk = NA / 16;               // 9216 floats = 2304 float4
  const float4* row4 = (const float4*)(labels + (size_t)b * NA + blk * chunk);

  float4 v0 = row4[tid];
  float4 v1 = row4[tid + 1024];
  bool extra = tid < 256;                  // 2048 f4 by all, last 256 f4 by tid<256
  float4 v2 = extra ? row4[tid + 2048] : make_float4(0.f, 0.f, 0.f, 0.f);

  atomicAdd(&lh[mkey(v0.x) >> 18], 1u);
  atomicAdd(&lh[mkey(v0.y) >> 18], 1u);
  atomicAdd(&lh[mkey(v0.z) >> 18], 1u);
  atomicAdd(&lh[mkey(v0.w) >> 18], 1u);
  atomicAdd(&lh[mkey(v1.x) >> 18], 1u);
  atomicAdd(&lh[mkey(v1.y) >> 18], 1u);
  atomicAdd(&lh[mkey(v1.z) >> 18], 1u);
  atomicAdd(&lh[mkey(v1.w) >> 18], 1u);
  if (extra) {
    atomicAdd(&lh[mkey(v2.x) >> 18], 1u);
    atomicAdd(&lh[mkey(v2.y) >> 18], 1u);
    atomicAdd(&lh[mkey(v2.z) >> 18], 1u);
    atomicAdd(&lh[mkey(v2.w) >> 18], 1u);
  }

  float m = fmaxf(fmaxf(fmaxf(v0.x, v0.y), fmaxf(v0.z, v0.w)),
                  fmaxf(fmaxf(v1.x, v1.y), fmaxf(v1.z, v1.w)));
  if (extra) m = fmaxf(m, fmaxf(fmaxf(v2.x, v2.y), fmaxf(v2.z, v2.w)));
  float s = expf(v0.x - m) + expf(v0.y - m) + expf(v0.z - m) + expf(v0.w - m)
          + expf(v1.x - m) + expf(v1.y - m) + expf(v1.z - m) + expf(v1.w - m);
  if (extra)
    s += expf(v2.x - m) + expf(v2.y - m) + expf(v2.z - m) + expf(v2.w - m);

  rm[tid] = m; rs[tid] = s;
  __syncthreads();
  for (int off = 512; off > 0; off >>= 1) {
    if (tid < off) {
      float m1 = rm[tid], s1 = rs[tid];
      float m2 = rm[tid + off], s2 = rs[tid + off];
      float M = fmaxf(m1, m2);
      rm[tid] = M;
      rs[tid] = s1 * expf(m1 - M) + s2 * expf(m2 - M);
    }
    __syncthreads();
  }
  if (tid == 0) partial[blockIdx.x] = make_float2(rm[0], rs[0]);

  unsigned short* out = hp + (size_t)blockIdx.x * NBINS;
  for (int i = tid; i < NBINS; i += 1024) out[i] = (unsigned short)lh[i];
}

// ---------------- K2: sum private hists, finalize (m,S), threshold bin -------
__global__ __launch_bounds__(1024) void k_threshold(const unsigned short* __restrict__ hp,
                                                    const float2* __restrict__ partial,
                                                    float4* __restrict__ meta) {
  int b = blockIdx.x;
  __shared__ unsigned lh[NBINS];           // 64KB summed histogram
  __shared__ float red_m, red_s;
  __shared__ unsigned cs[1024];
  int t = threadIdx.x;

  for (int i = t; i < NBINS / 2; i += 1024) {   // uint load = 2 bins
    unsigned s0 = 0, s1 = 0;
#pragma unroll
    for (int c = 0; c < 16; ++c) {
      unsigned u = *(const unsigned*)&hp[(size_t)(b * 16 + c) * NBINS + i * 2];
      s0 += u & 0xFFFFu; s1 += u >> 16;
    }
    lh[i * 2] = s0; lh[i * 2 + 1] = s1;
  }
  if (t == 0) {
    float m = -INFINITY, s = 0.f;
    for (int i = 0; i < 16; ++i) {
      float2 p = partial[b * 16 + i];
      float M = fmaxf(m, p.x);
      s = s * expf(m - M) + p.y * expf(p.x - M);
      m = M;
    }
    red_m = m; red_s = s;
  }
  __syncthreads();

  unsigned local[16], lsum = 0;
  for (int q = 0; q < 16; ++q) {            // rank r = t*16+q, bin = NBINS-1-r
    local[q] = lh[NBINS - 1 - (t * 16 + q)];
    lsum += local[q];
  }
  cs[t] = lsum;
  __syncthreads();
  for (int off = 1; off < 1024; off <<= 1) {  // Hillis-Steele inclusive scan
    unsigned v = (t >= off) ? cs[t - off] : 0u;
    __syncthreads();
    cs[t] += v;
    __syncthreads();
  }
  unsigned incl = cs[t], excl = incl - lsum;
  if (excl < NPOST && incl >= NPOST) {
    unsigned running = excl;
    for (int q = 0; q < 16; ++q) {
      unsigned c = local[q];
      if (running < NPOST && running + c >= NPOST) {
        unsigned bin = NBINS - 1 - (t * 16 + q);
        meta[b] = make_float4(red_m, red_s, __uint_as_float(bin), 0.f);
      }
      running += c;
    }
  }
}

// ---------------- K3: compact + presort segment (first 28 bitonic passes) ----
__global__ __launch_bounds__(256) void k_compact(const float* __restrict__ labels,
                                                 const float4* __restrict__ meta,
                                                 ull* __restrict__ cand) {
  int b = blockIdx.x >> 4, blk = blockIdx.x & 15;
  unsigned tb = __float_as_uint(meta[b].z);
  const int chunk = NA / 16;               // 9216 floats = 2304 float4
  const float4* row4 = (const float4*)(labels + (size_t)b * NA + blk * chunk);
  int tid = threadIdx.x;

  float4 v[9];
#pragma unroll
  for (int it = 0; it < 9; ++it)
    v[it] = row4[it * 256 + tid];

  unsigned c = 0;
#pragma unroll
  for (int it = 0; it < 9; ++it) {
    c += ((mkey(v[it].x) >> 18) >= tb);
    c += ((mkey(v[it].y) >> 18) >= tb);
    c += ((mkey(v[it].z) >> 18) >= tb);
    c += ((mkey(v[it].w) >> 18) >= tb);
  }

  __shared__ unsigned ssum[256];
  __shared__ ull seg[SEG];
  if (tid < SEG) seg[tid] = 0ULL;
  ssum[tid] = c;
  __syncthreads();
  for (int off = 1; off < 256; off <<= 1) {
    unsigned t = (tid >= off) ? ssum[tid - off] : 0u;
    __syncthreads();
    ssum[tid] += t;
    __syncthreads();
  }
  unsigned pos = ssum[tid] - c;            // exclusive prefix

  if (c) {
#pragma unroll
    for (int it = 0; it < 9; ++it) {
      float vals[4] = {v[it].x, v[it].y, v[it].z, v[it].w};
#pragma unroll
      for (int j = 0; j < 4; ++j) {
        unsigned kk = mkey(vals[j]);
        if ((kk >> 18) >= tb) {
          unsigned idx = (unsigned)(blk * chunk + (it * 256 + tid) * 4 + j);
          if (pos < SEG) seg[pos] = ((ull)kk << 32) | (unsigned)~idx;
          pos++;
        }
      }
    }
  }
  __syncthreads();

  // bitonic stages k=2..128 within the segment (descending run)
  for (int k = 2; k <= SEG; k <<= 1) {
    for (int j = k >> 1; j > 0; j >>= 1) {
      if (tid < SEG) {
        int e = tid, x = e ^ j;
        if (x > e) {
          ull a = seg[e], cc = seg[x];
          bool up = (e & k) == 0;
          if (up ? (a < cc) : (a > cc)) { seg[e] = cc; seg[x] = a; }
        }
      }
      __syncthreads();
    }
  }

  ull* cb = cand + (size_t)b * CAND_CAP + blk * SEG;
  if (tid < SEG) cb[tid] = seg[tid];
}

// ---------------- K4: exact rank via binary search in 16 sorted runs ---------
__global__ __launch_bounds__(512) void k_rank_emit(const ull* __restrict__ cand,
                                                   const float4* __restrict__ meta,
                                                   const float* __restrict__ labels,
                                                   const float* __restrict__ deltas,
                                                   const float4* __restrict__ anchors,
                                                   const float* __restrict__ variances,
                                                   float4* __restrict__ sboxes,
                                                   float* __restrict__ sscores) {
  int b = blockIdx.x >> 2, part = blockIdx.x & 3;
  __shared__ ull sd[CAND_CAP];
  for (int i = threadIdx.x; i < CAND_CAP; i += 512)
    sd[i] = cand[(size_t)b * CAND_CAP + i];  // 16 sorted (desc) 128-runs
  __syncthreads();

  ull x = sd[part * 512 + threadIdx.x];
  if (x == 0ULL) return;                     // zero-pad: rank >= 1000 anyway

  int rank = 0;
#pragma unroll
  for (int t = 0; t < 16; ++t) {
    const ull* run = &sd[t << 7];
    int p = 0;
    if (run[p + 63] > x) p += 64;
    if (run[p + 31] > x) p += 32;
    if (run[p + 15] > x) p += 16;
    if (run[p + 7]  > x) p += 8;
    if (run[p + 3]  > x) p += 4;
    if (run[p + 1]  > x) p += 2;
    if (run[p]      > x) p += 1;
    rank += p;
  }
  if (rank >= NPOST) return;

  unsigned idx = ~(unsigned)(x & 0xFFFFFFFFu);
  float4 mt = meta[b];
  float lab = labels[(size_t)b * NA + idx];
  float score = expf(lab - mt.x) / mt.y;

  float4 an = anchors[idx];                  // [y1,x1,y2,x2]
  float aw = an.w - an.y;
  float ah = an.z - an.x;
  float acx = an.y + 0.5f * aw;
  float acy = an.x + 0.5f * ah;
  float4 dl = *(const float4*)(deltas + ((size_t)b * NA + idx) * 4);
  float4 var = *(const float4*)variances;
  float t0 = dl.x * var.x, t1 = dl.y * var.y, t2 = dl.z * var.z, t3 = dl.w * var.w;
  float bw = expf(t3) * aw;
  float bh = expf(t2) * ah;
  float bcx = t1 * aw + acx;
  float bcy = t0 * ah + acy;
  float y1 = bcy - 0.5f * bh, x1 = bcx - 0.5f * bw;
  float y2 = bh + y1, x2 = bw + x1;
  sboxes[(size_t)b * NPOST + rank] = make_float4(y1, x1, y2, x2);
  sscores[(size_t)b * NPOST + rank] = score;
}

// ---------------- K5: pairwise IoU, TRANSPOSED (lower-tri) bitmask -----------
__global__ __launch_bounds__(256) void k_mask(const float4* __restrict__ sboxes,
                                              ull* __restrict__ maskT) {
  int b = blockIdx.x / 63, tile = blockIdx.x % 63;
  __shared__ float4 bx[NPOST];               // 16KB
  for (int j = threadIdx.x; j < NPOST; j += 256) bx[j] = sboxes[(size_t)b * NPOST + j];
  __syncthreads();
  int il = threadIdx.x >> 4, w = threadIdx.x & 15;
  int i = tile * 16 + il;
  if (i < NPOST) {
    float4 bi = bx[i];
    float ay1 = bi.x, ax1 = bi.y, ay2 = bi.z, ax2 = bi.w;
    float areai = (ay2 - ay1) * (ax2 - ax1);
    ull bits = 0;
    for (int jj = 0; jj < 64; ++jj) {
      int jb = (jj + w) & 63;                // skew to dodge LDS bank conflicts
      int j = (w << 6) + jb;
      if (j < i) {                           // lower-tri: rows j that suppress col i
        float4 bj = bx[j];
        float areaj = (bj.z - bj.x) * (bj.w - bj.y);
        float iy1 = fmaxf(ay1, bj.x), ix1 = fmaxf(ax1, bj.y);
        float iy2 = fminf(ay2, bj.z), ix2 = fminf(ax2, bj.w);
        float inter = fmaxf(iy2 - iy1, 0.f) * fmaxf(ix2 - ix1, 0.f);
        float uni = areai + areaj - inter;
        float iou = inter / fmaxf(uni, 1e-9f);
        if (iou > 0.7f) bits |= (1ull << jb);
      }
    }
    maskT[((size_t)b * NPOST + i) * 16 + w] = bits;
  }
}

// ---------------- K6: greedy NMS, fully unrolled, ballot-row chain -----------
__global__ __launch_bounds__(256, 1) void k_nms(const ull* __restrict__ maskT,
                                                const float4* __restrict__ sboxes,
                                                const float* __restrict__ sscores,
                                                float* __restrict__ out) {
  int b = blockIdx.x;
  __shared__ ull keep_lds[16];
  __shared__ int pref[17];
  int tid = threadIdx.x;

  if (tid < 64) {
    int lane = tid;
    const ull* MT = maskT + (size_t)b * NPOST * 16;

    ull colw[16], coln[16], ks[16];
#pragma unroll
    for (int k = 0; k < 16; ++k) { colw[k] = 0; coln[k] = 0; ks[k] = 0; }
    colw[0] = MT[(size_t)lane * 16 + 0];

#pragma unroll
    for (int w = 0; w < 16; ++w) {
      if (w < 15) {
        int nr = (w + 1) * 64 + lane; if (nr > NPOST - 1) nr = NPOST - 1;
#pragma unroll
        for (int k = 0; k < 16; ++k)
          if (k <= w + 1) coln[k] = MT[(size_t)nr * 16 + k];
      }

      ull acc = 0;
#pragma unroll
      for (int k = 0; k < 16; ++k)
        if (k < w) acc |= colw[k] & ks[k];
      ull rm0 = (w == 0) ? 0ull : __ballot(acc != 0ull);

      unsigned qlo = (unsigned)colw[w], qhi = (unsigned)(colw[w] >> 32);

      ull kmask = 0, supp = rm0;
#pragma unroll
      for (int bt = 0; bt < 4; ++bt) {
        ull rows[16];
        unsigned qd = (bt < 2) ? qlo : qhi;
#pragma unroll
        for (int r = 0; r < 16; ++r)
          rows[r] = __ballot(((qd >> ((bt & 1) * 16 + r)) & 1u) != 0u);
#pragma unroll
        for (int r = 0; r < 16; ++r) {
          int rr = bt * 16 + r;
          bool kp = ((supp >> rr) & 1ull) == 0ull;
          kmask |= kp ? (1ull << rr) : 0ull;
          supp  |= kp ? rows[r] : 0ull;
        }
      }
      if (w == 15) kmask &= (1ull << 40) - 1;   // boxes 1000..1023 invalid
      ks[w] = kmask;
      if (lane == 0) keep_lds[w] = kmask;

#pragma unroll
      for (int k = 0; k < 16; ++k) colw[k] = coln[k];
    }

    if (lane == 0) {
      int a = 0;
      for (int w = 0; w < 16; ++w) { pref[w] = a; a += __popcll(keep_lds[w]); }
      pref[16] = a;
    }
  }
  __syncthreads();

  int total = pref[16];
  float4* ob = (float4*)out;                 // boxes: 16*1000 float4
  float* os = out + (size_t)NB * NPOST * 4;  // scores: 16*1000 floats
  for (int r = tid; r < NPOST; r += 256) {
    if (r >= total) {
      ob[(size_t)b * NPOST + r] = make_float4(0.f, 0.f, 0.f, 0.f);
      os[(size_t)b * NPOST + r] = 0.f;
    }
  }
  for (int r = tid; r < NPOST; r += 256) {
    int w = r >> 6, bb = r & 63;
    ull kw = keep_lds[w];
    if ((kw >> bb) & 1ull) {
      int pos = pref[w] + __popcll(bb ? (kw & ((1ull << bb) - 1)) : 0ull);
      ob[(size_t)b * NPOST + pos] = sboxes[(size_t)b * NPOST + r];
      os[(size_t)b * NPOST + pos] = sscores[(size_t)b * NPOST + r];
    }
  }
}

extern "C" void kernel_launch(void* const* d_in, const int* in_sizes, int n_in,
                              void* d_out, int out_size, void* d_ws, size_t ws_size,
                              hipStream_t stream) {
  const float* deltas    = (const float*)d_in[0];
  const float* labels    = (const float*)d_in[1];
  const float* anchors   = (const float*)d_in[2];
  const float* variances = (const float*)d_in[3];

  char* ws = (char*)d_ws;
  ull*            cand    = (ull*)(ws + OFF_CAND);
  ull*            maskT   = (ull*)(ws + OFF_MASK);
  unsigned short* hp      = (unsigned short*)(ws + OFF_HP);
  float2*         partial = (float2*)(ws + OFF_PART);
  float4*         meta    = (float4*)(ws + OFF_META);
  float4*         sboxes  = (float4*)(ws + OFF_SBOX);
  float*          sscores = (float*)(ws + OFF_SSCORE);

  k_reduce_hist<<<NB * 16, 1024, 0, stream>>>(labels, hp, partial);
  k_threshold<<<NB, 1024, 0, stream>>>(hp, partial, meta);
  k_compact<<<NB * 16, 256, 0, stream>>>(labels, meta, cand);
  k_rank_emit<<<NB * 4, 512, 0, stream>>>(cand, meta, labels, deltas,
                                          (const float4*)anchors, variances,
                                          sboxes, sscores);
  k_mask<<<NB * 63, 256, 0, stream>>>(sboxes, maskT);
  k_nms<<<NB, 256, 0, stream>>>(maskT, sboxes, sscores, (float*)d_out);
}

// Round 16
// 74.171 us; speedup vs baseline: 1.8057x; 1.1684x over previous
//
#include <hip/hip_runtime.h>

typedef unsigned long long ull;

#define NA 147456
#define NB 16
#define NBINS 16384        // top-14 bits of monotonic key
#define CAND_CAP 2048
#define SEG 128
#define NPOST 1000

// ws layout (bytes)
#define OFF_CAND    0                    // 16*2048*8    = 262144
#define OFF_MASK    262144               // 16*1000*16*8 = 2048000 (maskT)
#define OFF_PART    2310144              // 256*8        = 2048
#define OFF_SBOX    2312192              // 16*1000*16   = 256000
#define OFF_SSCORE  2568192              // 16*1000*4    = 64000

__device__ __forceinline__ unsigned mkey(float f) {
  unsigned u = __float_as_uint(f);
  return u ^ ((unsigned)((int)u >> 31) | 0x80000000u);  // monotonic: bigger float -> bigger key
}

// ---------------- K1: fused softmax-reduce + LOCAL top-128 select ------------
// Per block (one 9216-chunk): LDS hist -> wave-shuffle scan finds local bin T
// (top-down cum crosses 128) -> compact bins>=T (<256) -> wave-0 register
// bitonic 256-sort (shfl, barrier-free) -> write exact sorted top-128 segment.
// No global threshold, no hp traffic, no separate threshold/compact kernels.
__global__ __launch_bounds__(1024) void k_select(const float* __restrict__ labels,
                                                 ull* __restrict__ cand,
                                                 float2* __restrict__ partial) {
  int b = blockIdx.x >> 4, blk = blockIdx.x & 15;
  __shared__ unsigned lh[NBINS];           // 64KB
  __shared__ ull sb[256];
  __shared__ float2 wlds[16];
  __shared__ unsigned wsums[16];
  __shared__ unsigned cntT;
  __shared__ int Tlds;
  int tid = threadIdx.x;
  int lane = tid & 63, wid = tid >> 6;
  for (int i = tid; i < NBINS; i += 1024) lh[i] = 0;
  if (tid < 256) sb[tid] = 0ULL;
  if (tid == 0) cntT = 0;
  __syncthreads();

  const int chunk = NA / 16;               // 9216 floats = 2304 float4
  const float4* row4 = (const float4*)(labels + (size_t)b * NA + blk * chunk);

  float4 v0 = row4[tid];
  float4 v1 = row4[tid + 1024];
  bool extra = tid < 256;
  float4 v2 = extra ? row4[tid + 2048] : make_float4(0.f, 0.f, 0.f, 0.f);

  atomicAdd(&lh[mkey(v0.x) >> 18], 1u);
  atomicAdd(&lh[mkey(v0.y) >> 18], 1u);
  atomicAdd(&lh[mkey(v0.z) >> 18], 1u);
  atomicAdd(&lh[mkey(v0.w) >> 18], 1u);
  atomicAdd(&lh[mkey(v1.x) >> 18], 1u);
  atomicAdd(&lh[mkey(v1.y) >> 18], 1u);
  atomicAdd(&lh[mkey(v1.z) >> 18], 1u);
  atomicAdd(&lh[mkey(v1.w) >> 18], 1u);
  if (extra) {
    atomicAdd(&lh[mkey(v2.x) >> 18], 1u);
    atomicAdd(&lh[mkey(v2.y) >> 18], 1u);
    atomicAdd(&lh[mkey(v2.z) >> 18], 1u);
    atomicAdd(&lh[mkey(v2.w) >> 18], 1u);
  }

  // per-thread softmax partial, wave shuffle reduce, leaders -> LDS
  float m = fmaxf(fmaxf(fmaxf(v0.x, v0.y), fmaxf(v0.z, v0.w)),
                  fmaxf(fmaxf(v1.x, v1.y), fmaxf(v1.z, v1.w)));
  if (extra) m = fmaxf(m, fmaxf(fmaxf(v2.x, v2.y), fmaxf(v2.z, v2.w)));
  float s = expf(v0.x - m) + expf(v0.y - m) + expf(v0.z - m) + expf(v0.w - m)
          + expf(v1.x - m) + expf(v1.y - m) + expf(v1.z - m) + expf(v1.w - m);
  if (extra)
    s += expf(v2.x - m) + expf(v2.y - m) + expf(v2.z - m) + expf(v2.w - m);
  for (int off = 32; off > 0; off >>= 1) {
    float m2 = __shfl_down(m, off);
    float s2 = __shfl_down(s, off);
    float M = fmaxf(m, m2);
    s = s * expf(m - M) + s2 * expf(m2 - M);
    m = M;
  }
  if (lane == 0) wlds[wid] = make_float2(m, s);
  __syncthreads();                         // hist complete + wlds complete
  if (tid == 0) {
    float mm = -INFINITY, ss = 0.f;
    for (int i = 0; i < 16; ++i) {
      float2 p = wlds[i];
      float M = fmaxf(mm, p.x);
      ss = ss * expf(mm - M) + p.y * expf(p.x - M);
      mm = M;
    }
    partial[blockIdx.x] = make_float2(mm, ss);
  }

  // descending scan: thread t owns ranks [t*16, t*16+16)
  unsigned lsum = 0;
  unsigned lbin[16];
#pragma unroll
  for (int q = 0; q < 16; ++q) {
    lbin[q] = lh[NBINS - 1 - (tid * 16 + q)];
    lsum += lbin[q];
  }
  unsigned p = lsum;                       // wave inclusive prefix
  for (int d = 1; d < 64; d <<= 1) {
    unsigned t = __shfl_up(p, d);
    if (lane >= d) p += t;
  }
  if (lane == 63) wsums[wid] = p;
  __syncthreads();
  unsigned wexcl = 0;
#pragma unroll
  for (int w = 0; w < 16; ++w) wexcl += (w < wid) ? wsums[w] : 0u;
  unsigned excl = wexcl + p - lsum;
  unsigned incl = excl + lsum;
  if (excl < SEG && incl >= SEG) {         // crossing thread: find T
    unsigned running = excl;
#pragma unroll
    for (int q = 0; q < 16; ++q) {
      unsigned c = lbin[q];
      if (running < SEG && running + c >= SEG) Tlds = NBINS - 1 - (tid * 16 + q);
      running += c;
    }
  }
  __syncthreads();
  unsigned T = (unsigned)Tlds;

  // compact all elements with bin >= T (128..~137 of them) into sb
  {
    float vals[12] = {v0.x, v0.y, v0.z, v0.w, v1.x, v1.y, v1.z, v1.w,
                      v2.x, v2.y, v2.z, v2.w};
    int nv = extra ? 12 : 8;
    for (int c = 0; c < nv; ++c) {
      unsigned kk = mkey(vals[c]);
      if ((kk >> 18) >= T) {
        unsigned pos = atomicAdd(&cntT, 1u);
        int f4i = (c < 4) ? tid : (c < 8) ? (tid + 1024) : (tid + 2048);
        unsigned idx = (unsigned)(blk * chunk + f4i * 4 + (c & 3));
        if (pos < 256) sb[pos] = ((ull)kk << 32) | (unsigned)~idx;
      }
    }
  }
  __syncthreads();

  // wave 0: register bitonic sort of 256 (4 elems/lane), no barriers
  if (tid < 64) {
    ull v[4];
#pragma unroll
    for (int r = 0; r < 4; ++r) v[r] = sb[tid * 4 + r];
#pragma unroll
    for (int k = 2; k <= 256; k <<= 1) {
#pragma unroll
      for (int jl = 256; jl > 0; jl >>= 1) {
        int j = jl >> 1;
        if (j == 0 || j >= k) continue;    // j runs k/2..1
        if (j >= 4) {
          int lx = j >> 2;
#pragma unroll
          for (int r = 0; r < 4; ++r) {
            ull other = __shfl_xor(v[r], lx);
            int e = tid * 4 + r;
            bool up = (e & k) == 0;
            bool lower = (e & j) == 0;
            bool keep_max = (lower == up);
            bool gt = v[r] > other;
            v[r] = (keep_max == gt) ? v[r] : other;
          }
        } else {
#pragma unroll
          for (int r = 0; r < 4; ++r) {
            int rp = r ^ j;
            if (rp > r) {
              int e = tid * 4 + r;
              bool up = (e & k) == 0;
              ull a = v[r], c2 = v[rp];
              if (up ? (a < c2) : (a > c2)) { v[r] = c2; v[rp] = a; }
            }
          }
        }
      }
    }
    // top-128 = elements e<128 = lanes 0..31
    if (tid < 32) {
      ull* cb = cand + (size_t)b * CAND_CAP + blk * SEG;
#pragma unroll
      for (int r = 0; r < 4; ++r) cb[tid * 4 + r] = v[r];
    }
  }
}

// ---------------- K2: exact rank via binary search + (m,S) finalize ----------
__global__ __launch_bounds__(512) void k_rank_emit(const ull* __restrict__ cand,
                                                   const float2* __restrict__ partial,
                                                   const float* __restrict__ labels,
                                                   const float* __restrict__ deltas,
                                                   const float4* __restrict__ anchors,
                                                   const float* __restrict__ variances,
                                                   float4* __restrict__ sboxes,
                                                   float* __restrict__ sscores) {
  int b = blockIdx.x >> 2, part = blockIdx.x & 3;
  __shared__ ull sd[CAND_CAP];
  __shared__ float2 msld;
  for (int i = threadIdx.x; i < CAND_CAP; i += 512)
    sd[i] = cand[(size_t)b * CAND_CAP + i];  // 16 sorted (desc) 128-runs
  if (threadIdx.x == 0) {                    // same serial order as before
    float m = -INFINITY, s = 0.f;
    for (int i = 0; i < 16; ++i) {
      float2 pp = partial[b * 16 + i];
      float M = fmaxf(m, pp.x);
      s = s * expf(m - M) + pp.y * expf(pp.x - M);
      m = M;
    }
    msld = make_float2(m, s);
  }
  __syncthreads();

  ull x = sd[part * 512 + threadIdx.x];
  int rank = 0;
#pragma unroll
  for (int t = 0; t < 16; ++t) {
    const ull* run = &sd[t << 7];
    int p = 0;
    if (run[p + 63] > x) p += 64;
    if (run[p + 31] > x) p += 32;
    if (run[p + 15] > x) p += 16;
    if (run[p + 7]  > x) p += 8;
    if (run[p + 3]  > x) p += 4;
    if (run[p + 1]  > x) p += 2;
    if (run[p]      > x) p += 1;
    rank += p;
  }
  if (rank >= NPOST) return;

  unsigned idx = ~(unsigned)(x & 0xFFFFFFFFu);
  float2 mt = msld;
  float lab = labels[(size_t)b * NA + idx];
  float score = expf(lab - mt.x) / mt.y;

  float4 an = anchors[idx];                  // [y1,x1,y2,x2]
  float aw = an.w - an.y;
  float ah = an.z - an.x;
  float acx = an.y + 0.5f * aw;
  float acy = an.x + 0.5f * ah;
  float4 dl = *(const float4*)(deltas + ((size_t)b * NA + idx) * 4);
  float4 var = *(const float4*)variances;
  float t0 = dl.x * var.x, t1 = dl.y * var.y, t2 = dl.z * var.z, t3 = dl.w * var.w;
  float bw = expf(t3) * aw;
  float bh = expf(t2) * ah;
  float bcx = t1 * aw + acx;
  float bcy = t0 * ah + acy;
  float y1 = bcy - 0.5f * bh, x1 = bcx - 0.5f * bw;
  float y2 = bh + y1, x2 = bw + x1;
  sboxes[(size_t)b * NPOST + rank] = make_float4(y1, x1, y2, x2);
  sscores[(size_t)b * NPOST + rank] = score;
}

// ---------------- K3: pairwise IoU, TRANSPOSED (lower-tri) bitmask -----------
__global__ __launch_bounds__(256) void k_mask(const float4* __restrict__ sboxes,
                                              ull* __restrict__ maskT) {
  int b = blockIdx.x / 63, tile = blockIdx.x % 63;
  __shared__ float4 bx[NPOST];               // 16KB
  for (int j = threadIdx.x; j < NPOST; j += 256) bx[j] = sboxes[(size_t)b * NPOST + j];
  __syncthreads();
  int il = threadIdx.x >> 4, w = threadIdx.x & 15;
  int i = tile * 16 + il;
  if (i < NPOST) {
    float4 bi = bx[i];
    float ay1 = bi.x, ax1 = bi.y, ay2 = bi.z, ax2 = bi.w;
    float areai = (ay2 - ay1) * (ax2 - ax1);
    ull bits = 0;
    for (int jj = 0; jj < 64; ++jj) {
      int jb = (jj + w) & 63;                // skew to dodge LDS bank conflicts
      int j = (w << 6) + jb;
      if (j < i) {                           // lower-tri: rows j that suppress col i
        float4 bj = bx[j];
        float areaj = (bj.z - bj.x) * (bj.w - bj.y);
        float iy1 = fmaxf(ay1, bj.x), ix1 = fmaxf(ax1, bj.y);
        float iy2 = fminf(ay2, bj.z), ix2 = fminf(ax2, bj.w);
        float inter = fmaxf(iy2 - iy1, 0.f) * fmaxf(ix2 - ix1, 0.f);
        float uni = areai + areaj - inter;
        float iou = inter / fmaxf(uni, 1e-9f);
        if (iou > 0.7f) bits |= (1ull << jb);
      }
    }
    maskT[((size_t)b * NPOST + i) * 16 + w] = bits;
  }
}

// ---------------- K4: greedy NMS, fully unrolled, ballot-row chain -----------
__global__ __launch_bounds__(256, 1) void k_nms(const ull* __restrict__ maskT,
                                                const float4* __restrict__ sboxes,
                                                const float* __restrict__ sscores,
                                                float* __restrict__ out) {
  int b = blockIdx.x;
  __shared__ ull keep_lds[16];
  __shared__ int pref[17];
  int tid = threadIdx.x;

  if (tid < 64) {
    int lane = tid;
    const ull* MT = maskT + (size_t)b * NPOST * 16;

    ull colw[16], coln[16], ks[16];
#pragma unroll
    for (int k = 0; k < 16; ++k) { colw[k] = 0; coln[k] = 0; ks[k] = 0; }
    colw[0] = MT[(size_t)lane * 16 + 0];

#pragma unroll
    for (int w = 0; w < 16; ++w) {
      if (w < 15) {
        int nr = (w + 1) * 64 + lane; if (nr > NPOST - 1) nr = NPOST - 1;
#pragma unroll
        for (int k = 0; k < 16; ++k)
          if (k <= w + 1) coln[k] = MT[(size_t)nr * 16 + k];
      }

      ull acc = 0;
#pragma unroll
      for (int k = 0; k < 16; ++k)
        if (k < w) acc |= colw[k] & ks[k];
      ull rm0 = (w == 0) ? 0ull : __ballot(acc != 0ull);

      unsigned qlo = (unsigned)colw[w], qhi = (unsigned)(colw[w] >> 32);

      ull kmask = 0, supp = rm0;
#pragma unroll
      for (int bt = 0; bt < 4; ++bt) {
        ull rows[16];
        unsigned qd = (bt < 2) ? qlo : qhi;
#pragma unroll
        for (int r = 0; r < 16; ++r)
          rows[r] = __ballot(((qd >> ((bt & 1) * 16 + r)) & 1u) != 0u);
#pragma unroll
        for (int r = 0; r < 16; ++r) {
          int rr = bt * 16 + r;
          bool kp = ((supp >> rr) & 1ull) == 0ull;
          kmask |= kp ? (1ull << rr) : 0ull;
          supp  |= kp ? rows[r] : 0ull;
        }
      }
      if (w == 15) kmask &= (1ull << 40) - 1;   // boxes 1000..1023 invalid
      ks[w] = kmask;
      if (lane == 0) keep_lds[w] = kmask;

#pragma unroll
      for (int k = 0; k < 16; ++k) colw[k] = coln[k];
    }

    if (lane == 0) {
      int a = 0;
      for (int w = 0; w < 16; ++w) { pref[w] = a; a += __popcll(keep_lds[w]); }
      pref[16] = a;
    }
  }
  __syncthreads();

  int total = pref[16];
  float4* ob = (float4*)out;                 // boxes: 16*1000 float4
  float* os = out + (size_t)NB * NPOST * 4;  // scores: 16*1000 floats
  for (int r = tid; r < NPOST; r += 256) {
    if (r >= total) {
      ob[(size_t)b * NPOST + r] = make_float4(0.f, 0.f, 0.f, 0.f);
      os[(size_t)b * NPOST + r] = 0.f;
    }
  }
  for (int r = tid; r < NPOST; r += 256) {
    int w = r >> 6, bb = r & 63;
    ull kw = keep_lds[w];
    if ((kw >> bb) & 1ull) {
      int pos = pref[w] + __popcll(bb ? (kw & ((1ull << bb) - 1)) : 0ull);
      ob[(size_t)b * NPOST + pos] = sboxes[(size_t)b * NPOST + r];
      os[(size_t)b * NPOST + pos] = sscores[(size_t)b * NPOST + r];
    }
  }
}

extern "C" void kernel_launch(void* const* d_in, const int* in_sizes, int n_in,
                              void* d_out, int out_size, void* d_ws, size_t ws_size,
                              hipStream_t stream) {
  const float* deltas    = (const float*)d_in[0];
  const float* labels    = (const float*)d_in[1];
  const float* anchors   = (const float*)d_in[2];
  const float* variances = (const float*)d_in[3];

  char* ws = (char*)d_ws;
  ull*     cand    = (ull*)(ws + OFF_CAND);
  ull*     maskT   = (ull*)(ws + OFF_MASK);
  float2*  partial = (float2*)(ws + OFF_PART);
  float4*  sboxes  = (float4*)(ws + OFF_SBOX);
  float*   sscores = (float*)(ws + OFF_SSCORE);

  k_select<<<NB * 16, 1024, 0, stream>>>(labels, cand, partial);
  k_rank_emit<<<NB * 4, 512, 0, stream>>>(cand, partial, labels, deltas,
                                          (const float4*)anchors, variances,
                                          sboxes, sscores);
  k_mask<<<NB * 63, 256, 0, stream>>>(sboxes, maskT);
  k_nms<<<NB, 256, 0, stream>>>(maskT, sboxes, sscores, (float*)d_out);
}